// Round 11
// baseline (261.648 us; speedup 1.0000x reference)
//
#include <hip/hip_runtime.h>

typedef unsigned short u16;
typedef unsigned int   u32;
typedef _Float16 f16;
typedef _Float16 h2  __attribute__((ext_vector_type(2)));
typedef _Float16 h8  __attribute__((ext_vector_type(8)));
typedef float    fx4 __attribute__((ext_vector_type(4)));

// ---- problem constants ----
// B=4 L=6 X=Y=8 -> 256 sites, W=49 window, D=256, h=8, dh=32
#define SCALE_Q 0.17677669529663687f

__device__ __forceinline__ u16 f2h_bits(float f){
  union{ f16 h; u16 u; } v; v.h = (f16)f; return v.u;
}
__device__ __forceinline__ u32 packh2(float a, float b){
  union{ h2 h; u32 u; } v; v.h = h2{(f16)a, (f16)b}; return v.u;
}
__device__ __forceinline__ h2 as_h2(u32 x){
  union{ u32 u; h2 h; } v; v.u = x; return v.h;
}
__device__ __forceinline__ h8 as_h8(uint4 u){
  union{ uint4 u; h8 h; } v; v.u = u; return v.h;
}
__device__ __forceinline__ float4 as_f4(uint4 u){
  union{ uint4 u; float4 f; } v; v.u = u; return v.f;
}

// diagnostic fill (fp32): encodes which runtime assumption failed
__global__ void flag_fill(float* out, int n, float v){
  int i = blockIdx.x*256 + threadIdx.x;
  if (i < n) out[i] = v;
}

// ---------------------------------------------------------------------------
// K0 (merged): fuse_w + fuse_b + fuse_qo in ONE launch. (unchanged)
// ---------------------------------------------------------------------------
__global__ __launch_bounds__(512) void fuse_all(
    const float* __restrict__ Wk, const float* __restrict__ Wv,
    const float* __restrict__ Ratt, const float* __restrict__ Rmsg,
    const float* __restrict__ Wq, const float* __restrict__ Wa,
    const float* __restrict__ bk, const float* __restrict__ bv,
    u16* __restrict__ Wft, float* __restrict__ bff,
    u16* __restrict__ Wqf, u16* __restrict__ Waf)
{
  const int blk = blockIdx.x;
  const int n = threadIdx.x;
  if (blk < 1024){
    const int rel = blk >> 8, d = blk & 255, ml = rel & 1;
    float acc = 0.f;
    if (n < 256) {
      const int h = n >> 5, p = n & 31;
      const float* wcol = Wk + (size_t)ml*65536 + (size_t)(h*32)*256 + d;
      const float* rrow = Ratt + ((size_t)(rel*8 + h)*32 + p)*32;
      #pragma unroll
      for (int q = 0; q < 32; ++q) acc += wcol[q*256] * rrow[q];
    } else {
      const int n2 = n - 256, h = n2 >> 5, qq = n2 & 31;
      const float* wcol = Wv + (size_t)ml*65536 + (size_t)(h*32)*256 + d;
      const float* rcol = Rmsg + ((size_t)(rel*8 + h)*32)*32 + qq;
      #pragma unroll
      for (int p2 = 0; p2 < 32; ++p2) acc += wcol[p2*256] * rcol[p2*32];
    }
    Wft[(size_t)rel*131072 + (size_t)(d >> 5)*16384 + (size_t)n*32 + (d & 31)] = f2h_bits(acc);
  } else if (blk < 1028){
    const int rel = blk - 1024, ml = rel & 1;
    float acc = 0.f;
    if (n < 256) {
      const int h = n >> 5, p = n & 31;
      const float* rrow = Ratt + ((size_t)(rel*8 + h)*32 + p)*32;
      #pragma unroll
      for (int q = 0; q < 32; ++q) acc += bk[ml*256 + h*32 + q] * rrow[q];
    } else {
      const int n2 = n - 256, h = n2 >> 5, qq = n2 & 31;
      const float* rcol = Rmsg + ((size_t)(rel*8 + h)*32)*32 + qq;
      #pragma unroll
      for (int p2 = 0; p2 < 32; ++p2) acc += bv[ml*256 + h*32 + p2] * rcol[p2*32];
    }
    bff[rel*512 + n] = acc;
  } else {
    const int bb = blk - 1028;
    const int t = bb >> 8, d = bb & 255;
    if (n < 256){
      float v = Wq[(size_t)t*65536 + (size_t)n*256 + d] * SCALE_Q;
      Wqf[(size_t)t*65536 + (size_t)(d >> 5)*8192 + (size_t)n*32 + (d & 31)] = f2h_bits(v);
    } else {
      const int e = n - 256;
      float v = Wa[(size_t)t*65536 + (size_t)e*256 + d];
      Waf[(size_t)t*65536 + (size_t)(d >> 5)*8192 + (size_t)e*32 + (d & 31)] = f2h_bits(v);
    }
  }
}

// ---------------------------------------------------------------------------
// K1 v8: fused kw / v_msg projection GEMM — MFMA, TWO TILES PER BLOCK.
// (resubmission of r10 — audit found no hang/fault hazard; r10's container
//  failure presumed infra per r5 precedent. If it recurs, revert to v7b.)
// Each block does tiles (2p, 2p+1); tile-1's A (8 asm loads) + B prologue
// (12 asm loads) are issued before tile-0's epilogue, which uses RAW
// s_barrier + lgkmcnt(0) only (epilogue ordering is LDS-only) so the 20
// loads stay in flight across it. Grid nb*294 -> nb*147.
// ---------------------------------------------------------------------------
#define ASTRIDE 264   // u16 elements per LDS row (16B-aligned, conflict-light)

#define RAWBAR do{ asm volatile("s_waitcnt lgkmcnt(0)" ::: "memory"); \
                   __builtin_amdgcn_sched_barrier(0); \
                   __builtin_amdgcn_s_barrier(); }while(0)

// 8-step MFMA k-loop: 3-slot rotating B in breg, counted vmcnt (refills
// issued at steps 0..4; at step s>=3 the slot-(s%3) refill was issued at
// step s-3 -> wait vmcnt(8) leaves 8 newer loads in flight).
#define KLOOP(BPTR) do{ \
  _Pragma("unroll") \
  for (int s = 0; s < 8; ++s){ \
    if (s >= 3 && s <= 5)      { asm volatile("s_waitcnt vmcnt(8)" ::: "memory"); } \
    else if (s == 6)           { asm volatile("s_waitcnt vmcnt(4)" ::: "memory"); } \
    else if (s == 7)           { asm volatile("s_waitcnt vmcnt(0)" ::: "memory"); } \
    __builtin_amdgcn_sched_barrier(0); \
    h8 af[4]; \
    _Pragma("unroll") \
    for (int mt = 0; mt < 4; ++mt) \
      af[mt] = *(const h8*)(As + (mt*16)*ASTRIDE + s*32); \
    const int slot = s % 3; \
    _Pragma("unroll") \
    for (int j = 0; j < 4; ++j){ \
      h8 bf = as_h8(breg[slot][j]); \
      _Pragma("unroll") \
      for (int mt = 0; mt < 4; ++mt) \
        acc[mt][j] = __builtin_amdgcn_mfma_f32_16x16x32_f16(af[mt], bf, acc[mt][j], 0, 0, 0); \
    } \
    if (s < 5){ \
      _Pragma("unroll") \
      for (int j = 0; j < 4; ++j){ \
        const u16* ap = (BPTR) + (size_t)(s + 3)*16384 + j*512; \
        asm volatile("global_load_dwordx4 %0, %1, off" : "=v"(breg[slot][j]) : "v"(ap)); \
      } \
    } \
  } }while(0)

// Epilogue for one tile. BARRIER: RAWBAR (loads stay in flight) or __syncthreads.
#define EPILOGUE(BLOC, L, TILE, REL, BARRIER) do{ \
  const int row_ = tid >> 3, hsel = tid & 7; \
  const int r_g  = (TILE)*64 + row_; \
  const int xy   = r_g / 49, ef = r_g - xy*49; \
  _Pragma("unroll") \
  for (int half = 0; half < 2; ++half){ \
    BARRIER; \
    if ((wave >> 2) == half){ \
      _Pragma("unroll") \
      for (int j = 0; j < 4; ++j){ \
        const int n   = wave*64 + j*16 + l15; \
        const int col = n & 255; \
        const float biasv = bff[(REL)*512 + n]; \
        _Pragma("unroll") \
        for (int mt = 0; mt < 4; ++mt){ \
          _Pragma("unroll") \
          for (int reg = 0; reg < 4; ++reg){ \
            const int row = mt*16 + quad*4 + reg; \
            Smem[row*ASTRIDE + col] = f2h_bits(acc[mt][j][reg] + biasv); \
          } \
        } \
      } \
    } \
    BARRIER; \
    u16* dbuf = half ? vm : kw; \
    u16* dst  = dbuf + ((((size_t)((BLOC)*64 + xy)*8 + hsel)*6 + (L))*49 + ef)*32; \
    const u16* srcl = &Smem[row_*ASTRIDE + hsel*32]; \
    *(uint4*)(dst)      = *(const uint4*)(srcl); \
    *(uint4*)(dst + 8)  = *(const uint4*)(srcl + 8); \
    *(uint4*)(dst + 16) = *(const uint4*)(srcl + 16); \
    *(uint4*)(dst + 24) = *(const uint4*)(srcl + 24); \
  } }while(0)

__global__ __launch_bounds__(512) void gemm_kwv(
    const float* __restrict__ x, const int* __restrict__ mode,
    const u16* __restrict__ Wft, const float* __restrict__ bff,
    u16* __restrict__ kw, u16* __restrict__ vm, int b0)
{
  __shared__ u16 Smem[64*ASTRIDE];   // 33.8 KB: A-tile / epilogue transpose buf
  const int tid  = threadIdx.x;
  const int wave = tid >> 6, lane = tid & 63;
  const int quad = lane >> 4, l15 = lane & 15;

  // ---- tile params for the pair ----
  int bloc0, l0, tile0, rel0, bloc1, l1, tile1, rel1;
  const float *Ab0, *Ab1;
  const u16 *Bp0, *Bp1;
  {
    const int T0 = 2*blockIdx.x, T1 = T0 + 1;
    bloc0 = T0 / 294; { const int r = T0 % 294; l0 = r / 49; tile0 = r % 49; }
    bloc1 = T1 / 294; { const int r = T1 % 294; l1 = r / 49; tile1 = r % 49; }
    const int b0g = b0 + bloc0, b1g = b0 + bloc1;
    rel0 = mode[b0g*6]*2 + mode[b0g*6 + l0];
    rel1 = mode[b1g*6]*2 + mode[b1g*6 + l1];
    Ab0 = x + ((size_t)(b0g*6 + l0)*3136 + (size_t)tile0*64)*256;
    Ab1 = x + ((size_t)(b1g*6 + l1)*3136 + (size_t)tile1*64)*256;
    Bp0 = Wft + (size_t)rel0*131072 + (size_t)((wave << 6) + l15)*32 + (quad << 3);
    Bp1 = Wft + (size_t)rel1*131072 + (size_t)((wave << 6) + l15)*32 + (quad << 3);
  }

  // ---- tile0: B prologue (12 pinned loads, slots 0..2) ----
  uint4 breg[3][4];
  #pragma unroll
  for (int s = 0; s < 3; ++s)
    #pragma unroll
    for (int j = 0; j < 4; ++j){
      const u16* ap = Bp0 + (size_t)s*16384 + j*512;
      asm volatile("global_load_dwordx4 %0, %1, off" : "=v"(breg[s][j]) : "v"(ap));
    }

  // ---- tile0: A-stage (C++ loads, wave-linear coalesced) ----
  #pragma unroll
  for (int i = 0; i < 8; ++i){
    float4 f = *(const float4*)(Ab0 + (size_t)i*2048 + tid*4);
    const int row = i*8 + (tid >> 6), col = (tid & 63)*4;
    uint2 pk; pk.x = packh2(f.x, f.y); pk.y = packh2(f.z, f.w);
    *(uint2*)&Smem[row*ASTRIDE + col] = pk;
  }
  __syncthreads();   // full drain: tile0 slots 0..2 ready

  fx4 acc[4][4];
  #pragma unroll
  for (int mt = 0; mt < 4; ++mt)
    #pragma unroll
    for (int j = 0; j < 4; ++j) acc[mt][j] = fx4{0,0,0,0};

  const u16* As = &Smem[l15*ASTRIDE + (quad << 3)];

  KLOOP(Bp0);

  // ---- prefetch tile1: A (8 pinned loads) + B prologue (12 pinned loads).
  // These stay in flight across tile0's raw-barrier epilogue. ----
  uint4 aR[8];
  #pragma unroll
  for (int i = 0; i < 8; ++i){
    const float* ap = Ab1 + (size_t)i*2048 + tid*4;
    asm volatile("global_load_dwordx4 %0, %1, off" : "=v"(aR[i]) : "v"(ap));
  }
  #pragma unroll
  for (int s = 0; s < 3; ++s)
    #pragma unroll
    for (int j = 0; j < 4; ++j){
      const u16* ap = Bp1 + (size_t)s*16384 + j*512;
      asm volatile("global_load_dwordx4 %0, %1, off" : "=v"(breg[s][j]) : "v"(ap));
    }

  // ---- tile0 epilogue: RAW barriers (lgkm-only; vm loads uninterrupted) ----
  EPILOGUE(bloc0, l0, tile0, rel0, RAWBAR);

  RAWBAR;   // all waves' Smem reads complete before A(t1) overwrite

  // ---- tile1: A/B arrived during the epilogue; stage A ----
  asm volatile("s_waitcnt vmcnt(0)" ::: "memory");
  __builtin_amdgcn_sched_barrier(0);
  #pragma unroll
  for (int i = 0; i < 8; ++i){
    float4 f = as_f4(aR[i]);
    const int row = i*8 + (tid >> 6), col = (tid & 63)*4;
    uint2 pk; pk.x = packh2(f.x, f.y); pk.y = packh2(f.z, f.w);
    *(uint2*)&Smem[row*ASTRIDE + col] = pk;
  }
  RAWBAR;   // A(t1) visible to all waves

  #pragma unroll
  for (int mt = 0; mt < 4; ++mt)
    #pragma unroll
    for (int j = 0; j < 4; ++j) acc[mt][j] = fx4{0,0,0,0};

  KLOOP(Bp1);

  // ---- tile1 epilogue: normal barriers ----
  EPILOGUE(bloc1, l1, tile1, rel1, __syncthreads());
}

// ---------------------------------------------------------------------------
// K2 v2: q projection (l=0 only) — MFMA. BM=32, BN=256, grid = 4*98. (unchanged)
// ---------------------------------------------------------------------------
__global__ __launch_bounds__(256, 2) void gemm_qp(
    const float* __restrict__ x, const int* __restrict__ mode,
    const u16* __restrict__ Wqf, const float* __restrict__ bq,
    u16* __restrict__ qbuf)
{
  __shared__ u16 Smem[32*ASTRIDE];
  const int rowT = blockIdx.x;       // b*98 + tile
  const int b = rowT / 98, tile = rowT % 98;
  const int m0 = mode[b*6];
  const float* Abase = x + ((size_t)(b*6)*3136 + (size_t)tile*32)*256;
  const int tid = threadIdx.x;
  const int wave = tid >> 6, lane = tid & 63;
  const int quad = lane >> 4, l15 = lane & 15;

  const u16* Bp = Wqf + (size_t)m0*65536 + (size_t)((wave << 6) + l15)*32 + (quad << 3);
  uint4 breg[32];
  #pragma unroll
  for (int s = 0; s < 8; ++s)
    #pragma unroll
    for (int j = 0; j < 4; ++j){
      const u16* ap = Bp + (size_t)s*8192 + j*512;
      asm volatile("global_load_dwordx4 %0, %1, off" : "=v"(breg[s*4+j]) : "v"(ap));
    }

  {
    const int r = tid >> 3, cseg = (tid & 7)*32;
    const float* src = Abase + (size_t)r*256 + cseg;
    u16* dst = &Smem[r*ASTRIDE + cseg];
    #pragma unroll
    for (int i = 0; i < 4; ++i){
      float4 f0 = *(const float4*)(src + i*8);
      float4 f1 = *(const float4*)(src + i*8 + 4);
      uint4 pk;
      pk.x = packh2(f0.x, f0.y); pk.y = packh2(f0.z, f0.w);
      pk.z = packh2(f1.x, f1.y); pk.w = packh2(f1.z, f1.w);
      *(uint4*)(dst + i*8) = pk;
    }
  }
  __syncthreads();

  fx4 acc[2][4];
  #pragma unroll
  for (int mt = 0; mt < 2; ++mt)
    #pragma unroll
    for (int j = 0; j < 4; ++j) acc[mt][j] = fx4{0,0,0,0};

  const u16* As0 = &Smem[l15*ASTRIDE + (quad << 3)];
  const u16* As1 = As0 + 16*ASTRIDE;
  asm volatile("s_waitcnt vmcnt(0)" ::: "memory");
  __builtin_amdgcn_sched_barrier(0);
  #pragma unroll
  for (int s = 0; s < 8; ++s){
    h8 af0 = *(const h8*)(As0 + s*32);
    h8 af1 = *(const h8*)(As1 + s*32);
    #pragma unroll
    for (int j = 0; j < 4; ++j){
      h8 bf = as_h8(breg[s*4+j]);
      acc[0][j] = __builtin_amdgcn_mfma_f32_16x16x32_f16(af0, bf, acc[0][j], 0, 0, 0);
      acc[1][j] = __builtin_amdgcn_mfma_f32_16x16x32_f16(af1, bf, acc[1][j], 0, 0, 0);
    }
  }

  __syncthreads();
  #pragma unroll
  for (int j = 0; j < 4; ++j){
    const int n = wave*64 + j*16 + l15;
    const float bias = bq[m0*256 + n] * SCALE_Q;
    #pragma unroll
    for (int mt = 0; mt < 2; ++mt)
      #pragma unroll
      for (int reg = 0; reg < 4; ++reg){
        const int row = mt*16 + quad*4 + reg;
        Smem[row*ASTRIDE + n] = f2h_bits(acc[mt][j][reg] + bias);
      }
  }
  __syncthreads();
  {
    const int row_ = tid >> 3, hsel = tid & 7;
    const int r_g = tile*32 + row_;
    const int xy = r_g / 49, ef = r_g - xy*49;
    u16* dst = qbuf + (((size_t)(b*64 + xy)*8 + hsel)*49 + ef)*32;
    const u16* srcl = &Smem[row_*ASTRIDE + hsel*32];
    *(uint4*)(dst)      = *(const uint4*)(srcl);
    *(uint4*)(dst + 8)  = *(const uint4*)(srcl + 8);
    *(uint4*)(dst + 16) = *(const uint4*)(srcl + 16);
    *(uint4*)(dst + 24) = *(const uint4*)(srcl + 24);
  }
}

// ---------------------------------------------------------------------------
// K3 v8: attention — ONE WAVE per (bloc,xy,h), MFMA, LDS double-buffer,
// all-C++ staging. (unchanged from r9 — passed)
// ---------------------------------------------------------------------------
#define LGKM0  do{ asm volatile("s_waitcnt lgkmcnt(0)" ::: "memory"); \
                   __builtin_amdgcn_sched_barrier(0); }while(0)

__device__ __forceinline__ void scatter_v(u16* VTb, int i4, uint4 vv){
  const int ef = i4 >> 2, pb = (i4 & 3)*8, c0 = ef >> 3;
  u16* vt = VTb + (ef & 7);
  vt[(pb+0)*64 + ((c0 ^ 0) << 3)] = (u16)(vv.x & 0xFFFFu);
  vt[(pb+1)*64 + ((c0 ^ 1) << 3)] = (u16)(vv.x >> 16);
  vt[(pb+2)*64 + ((c0 ^ 2) << 3)] = (u16)(vv.y & 0xFFFFu);
  vt[(pb+3)*64 + ((c0 ^ 3) << 3)] = (u16)(vv.y >> 16);
  vt[(pb+4)*64 + ((c0 ^ 4) << 3)] = (u16)(vv.z & 0xFFFFu);
  vt[(pb+5)*64 + ((c0 ^ 5) << 3)] = (u16)(vv.z >> 16);
  vt[(pb+6)*64 + ((c0 ^ 6) << 3)] = (u16)(vv.w & 0xFFFFu);
  vt[(pb+7)*64 + ((c0 ^ 7) << 3)] = (u16)(vv.w >> 16);
}

__global__ __launch_bounds__(64) void attn_kernel(
    const u16* __restrict__ qbuf, const u16* __restrict__ kw,
    const u16* __restrict__ vm,   const float* __restrict__ post,
    u16* __restrict__ aout, int b0)
{
  __shared__ u32 Ks[2*64*16];   // 2 buffers: K rows [ke][p], pad rows zero  8KB
  __shared__ u16 VT[2*32*64];   // 2 buffers: V^T [p][ke] chunk-XOR-swizzled 8KB
  __shared__ u16 PQ[64*64];     // Q staging [qi][32] -> P^T [qi][ke] swz    8KB
  __shared__ float poss[169];

  const int bloc  = blockIdx.x >> 9;
  const int local = blockIdx.x & 511;      // xy*8+h
  const int h = local & 7, xy = local >> 3;
  const int bxy = (b0 + bloc)*64 + xy;
  const int lane = threadIdx.x;            // 0..63
  const int quad = lane >> 4, l15 = lane & 15;

  const size_t kvbase = ((size_t)(bloc*64 + xy)*8 + h)*6;

  for (int i = lane; i < 169; i += 64) poss[i] = post[i*8 + h];
  for (int i = lane; i < 480; i += 64){                     // K pad rows, both bufs
    const int bb = i / 240, o = i - bb*240;
    Ks[bb*1024 + 784 + o] = 0;
  }
  for (int i = lane; i < 1024; i += 64){                    // VT pad ke 48..63, both bufs
    const int bb = i >> 9, r = i & 511;
    const int p = r >> 4, ke = 48 + (r & 15);
    VT[bb*2048 + p*64 + ((((ke >> 3) ^ (p & 7)) & 7) << 3) + (ke & 7)] = 0;
  }
  { const u16* qsrc = qbuf + (size_t)(bxy*8 + h)*1568;      // Q rows -> PQ[qi][32]
    for (int i = lane; i < 196; i += 64)
      *(uint4*)&PQ[(i >> 2)*32 + (i & 3)*8] = *(const uint4*)(qsrc + (size_t)i*8);
    const uint4 z4 = make_uint4(0,0,0,0);
    for (int i = lane; i < 60; i += 64)                     // rows 49..63 zero
      *(uint4*)&PQ[1568 + i*8] = z4;
  }
  // ---- stage z=0 into buffer 0 ----
  { const uint4* ksrc = (const uint4*)((const u32*)kw + kvbase*784);
    for (int i = lane; i < 196; i += 64) ((uint4*)Ks)[i] = ksrc[i];
    const uint4* vsrc = (const uint4*)((const u32*)vm + kvbase*784);
    for (int i = lane; i < 196; i += 64) scatter_v(VT, i, vsrc[i]);
  }
  LGKM0;   // single-wave block: lgkmcnt(0) replaces __syncthreads

  // Q B-frags (persist across all z)
  h8 qf[4];
  #pragma unroll
  for (int nt = 0; nt < 4; ++nt)
    qf[nt] = *(const h8*)&PQ[(nt*16 + l15)*32 + quad*8];

  // bias C-in frags (persist): element (ke = mt*16+quad*4+reg, qi = nt*16+l15)
  fx4 bias[4][4];
  { int qa[4], qb[4];
    #pragma unroll
    for (int nt = 0; nt < 4; ++nt){
      const int qi = nt*16 + l15; qa[nt] = qi/7; qb[nt] = qi - qa[nt]*7;
    }
    #pragma unroll
    for (int mt = 0; mt < 4; ++mt)
      #pragma unroll
      for (int reg = 0; reg < 4; ++reg){
        const int ke = mt*16 + quad*4 + reg;
        const int ka = ke/7, kb = ke - ka*7;
        #pragma unroll
        for (int nt = 0; nt < 4; ++nt){
          const int qi = nt*16 + l15;
          float bv;
          if (ke > 48)      bv = -1e30f;
          else if (qi > 48) bv = 0.f;
          else              bv = poss[(qa[nt] - ka + 6)*13 + (qb[nt] - kb + 6)];
          bias[mt][nt][reg] = bv;
        }
      }
  }

  float mprev[4], lsum[4];
  fx4 Oacc[2][4];
  #pragma unroll
  for (int nt = 0; nt < 4; ++nt){
    mprev[nt] = -1e30f; lsum[nt] = 0.f;
    Oacc[0][nt] = fx4{0,0,0,0}; Oacc[1][nt] = fx4{0,0,0,0};
  }

  int cur = 0;
  for (int z = 0; z < 6; ++z){
    // ---- prefetch z+1 into C++ locals ----
    uint4 kn0, kn1, kn2, kn3, vn0, vn1, vn2, vn3;
    if (z < 5){
      const uint4* ksrc = (const uint4*)((const u32*)kw + (kvbase + z + 1)*784);
      const uint4* vsrc = (const uint4*)((const u32*)vm + (kvbase + z + 1)*784);
      kn0 = ksrc[lane]; kn1 = ksrc[64 + lane]; kn2 = ksrc[128 + lane];
      vn0 = vsrc[lane]; vn1 = vsrc[64 + lane]; vn2 = vsrc[128 + lane];
      if (lane < 4){ kn3 = ksrc[192 + lane]; vn3 = vsrc[192 + lane]; }
    }

    const u32* KsC = Ks + cur*1024;
    const u16* VTC = VT + cur*2048;

    // ---- S^T = K·Q^T + bias (16 MFMA) ----
    h8 kf[4];
    #pragma unroll
    for (int mt = 0; mt < 4; ++mt)
      kf[mt] = *(const h8*)((const u16*)KsC + (mt*16 + l15)*32 + quad*8);
    fx4 S[4][4];
    #pragma unroll
    for (int mt = 0; mt < 4; ++mt)
      #pragma unroll
      for (int nt = 0; nt < 4; ++nt)
        S[mt][nt] = __builtin_amdgcn_mfma_f32_16x16x32_f16(kf[mt], qf[nt], bias[mt][nt], 0, 0, 0);

    // ---- online softmax per qi-column group nt ----
    #pragma unroll
    for (int nt = 0; nt < 4; ++nt){
      float cm = S[0][nt][0];
      #pragma unroll
      for (int mt = 0; mt < 4; ++mt)
        #pragma unroll
        for (int r = 0; r < 4; ++r) cm = fmaxf(cm, S[mt][nt][r]);
      cm = fmaxf(cm, __shfl_xor(cm, 16));
      cm = fmaxf(cm, __shfl_xor(cm, 32));
      const float mnew = fmaxf(mprev[nt], cm);
      const float alpha = __expf(mprev[nt] - mnew);
      mprev[nt] = mnew;
      float sum = 0.f;
      #pragma unroll
      for (int mt = 0; mt < 4; ++mt)
        #pragma unroll
        for (int r = 0; r < 4; ++r){
          float e = __expf(S[mt][nt][r] - mnew); S[mt][nt][r] = e; sum += e;
        }
      sum += __shfl_xor(sum, 16);
      sum += __shfl_xor(sum, 32);
      lsum[nt] = lsum[nt]*alpha + sum;
      #pragma unroll
      for (int r = 0; r < 4; ++r){ Oacc[0][nt][r] *= alpha; Oacc[1][nt][r] *= alpha; }
    }

    // ---- pack P^T into PQ (swizzled): ke chunk = mt*2 + (quad>>1) ----
    #pragma unroll
    for (int nt = 0; nt < 4; ++nt){
      const int qi = nt*16 + l15;
      u16* prow = &PQ[qi*64 + ((quad & 1) << 2)];
      #pragma unroll
      for (int mt = 0; mt < 4; ++mt){
        const int chk = (mt*2 + (quad >> 1)) ^ (l15 & 7);
        uint2 w;
        w.x = packh2(S[mt][nt][0], S[mt][nt][1]);
        w.y = packh2(S[mt][nt][2], S[mt][nt][3]);
        *(uint2*)(prow + (chk << 3)) = w;
      }
    }
    LGKM0;   // P^T visible

    // ---- O^T += V^T · P^T (16 MFMA over 2 k-steps) ----
    #pragma unroll
    for (int ks = 0; ks < 2; ++ks){
      h8 vf[2];
      #pragma unroll
      for (int m2 = 0; m2 < 2; ++m2)
        vf[m2] = *(const h8*)&VTC[(m2*16 + l15)*64 + (((ks*4 + quad) ^ (l15 & 7)) << 3)];
      #pragma unroll
      for (int nt = 0; nt < 4; ++nt){
        h8 pf = *(const h8*)&PQ[(nt*16 + l15)*64 + (((ks*4 + quad) ^ (l15 & 7)) << 3)];
        Oacc[0][nt] = __builtin_amdgcn_mfma_f32_16x16x32_f16(vf[0], pf, Oacc[0][nt], 0, 0, 0);
        Oacc[1][nt] = __builtin_amdgcn_mfma_f32_16x16x32_f16(vf[1], pf, Oacc[1][nt], 0, 0, 0);
      }
    }

    // ---- stage z+1 into the OTHER buffer (WAR-free by construction) ----
    if (z < 5){
      u32* KsN = Ks + (cur ^ 1)*1024;
      u16* VTN = VT + (cur ^ 1)*2048;
      ((uint4*)KsN)[lane]       = kn0;
      ((uint4*)KsN)[64 + lane]  = kn1;
      ((uint4*)KsN)[128 + lane] = kn2;
      scatter_v(VTN, lane,       vn0);
      scatter_v(VTN, 64 + lane,  vn1);
      scatter_v(VTN, 128 + lane, vn2);
      if (lane < 4){
        ((uint4*)KsN)[192 + lane] = kn3;
        scatter_v(VTN, 192 + lane, vn3);
      }
    }
    LGKM0;   // staging visible before next iteration reads it
    cur ^= 1;
  }

  // ---- normalize + store via LDS roundtrip ----
  #pragma unroll
  for (int nt = 0; nt < 4; ++nt){
    const int qi = nt*16 + l15;
    if (qi < 49){
      const float inv = 1.f / lsum[nt];
      #pragma unroll
      for (int m2 = 0; m2 < 2; ++m2){
        uint2 w;
        w.x = packh2(Oacc[m2][nt][0]*inv, Oacc[m2][nt][1]*inv);
        w.y = packh2(Oacc[m2][nt][2]*inv, Oacc[m2][nt][3]*inv);
        *(uint2*)&PQ[qi*32 + m2*16 + quad*4] = w;
      }
    }
  }
  LGKM0;
  { u16* obase = aout + (size_t)bxy*12544 + h*32;
    for (int i = lane; i < 196; i += 64){
      const int r = i >> 2, c = (i & 3)*8;
      *(uint4*)(obase + (size_t)r*256 + c) = *(const uint4*)&PQ[r*32 + c];
    }
  }
}

// ---------------------------------------------------------------------------
// K4 v2: final projection — MFMA. A = aout f16, B = Waf[m0] k-step-major,
// bias ba, fp32 out via LDS float transpose. BM=32, BN=256, grid = 4*98.
// ---------------------------------------------------------------------------
__global__ __launch_bounds__(256, 2) void gemm_op(
    const u16* __restrict__ aout, const int* __restrict__ mode,
    const u16* __restrict__ Waf, const float* __restrict__ ba,
    float* __restrict__ outp)
{
  __shared__ float Smf[32*260];          // 33.3 KB; low half doubles as u16 A-tile
  u16* Smem = (u16*)Smf;
  const int rowT = blockIdx.x;       // b*98 + tile
  const int b = rowT / 98, tile = rowT % 98;
  const int m0 = mode[b*6];
  const u16* Abase = aout + ((size_t)b*3136 + (size_t)tile*32)*256;
  const int tid = threadIdx.x;
  const int wave = tid >> 6, lane = tid & 63;
  const int quad = lane >> 4, l15 = lane & 15;

  const u16* Bp = Waf + (size_t)m0*65536 + (size_t)((wave << 6) + l15)*32 + (quad << 3);
  uint4 breg[32];
  #pragma unroll
  for (int s = 0; s < 8; ++s)
    #pragma unroll
    for (int j = 0; j < 4; ++j){
      const u16* ap = Bp + (size_t)s*8192 + j*512;
      asm volatile("global_load_dwordx4 %0, %1, off" : "=v"(breg[s*4+j]) : "v"(ap));
    }

  {
    const int r = tid >> 3, cseg = (tid & 7)*32;
    const u16* src = Abase + (size_t)r*256 + cseg;
    u16* dst = &Smem[r*ASTRIDE + cseg];
    #pragma unroll
    for (int i = 0; i < 4; ++i)
      *(uint4*)(dst + i*8) = *(const uint4*)(src + i*8);
  }
  __syncthreads();

  fx4 acc[2][4];
  #pragma unroll
  for (int mt = 0; mt < 2; ++mt)
    #pragma unroll
    for (int j = 0; j < 4; ++j) acc[mt][j] = fx4{0,0,0,0};

  const u16* As0 = &Smem[l15*ASTRIDE + (quad << 3)];
  const u16* As1 = As0 + 16*ASTRIDE;
  asm volatile("s_waitcnt vmcnt(0)" ::: "memory");
  __builtin_amdgcn_sched_barrier(0);
  #pragma unroll
  for (int s = 0; s < 8; ++s){
    h8 af0 = *(const h8*)(As0 + s*32);
    h8 af1 = *(const h8*)(As1 + s*32);
    #pragma unroll
    for (int j = 0; j < 4; ++j){
      h8 bf = as_h8(breg[s*4+j]);
      acc[0][j] = __builtin_amdgcn_mfma_f32_16x16x32_f16(af0, bf, acc[0][j], 0, 0, 0);
      acc[1][j] = __builtin_amdgcn_mfma_f32_16x16x32_f16(af1, bf, acc[1][j], 0, 0, 0);
    }
  }

  __syncthreads();
  #pragma unroll
  for (int j = 0; j < 4; ++j){
    const int n = wave*64 + j*16 + l15;
    const float bias = ba[m0*256 + n];
    #pragma unroll
    for (int mt = 0; mt < 2; ++mt)
      #pragma unroll
      for (int reg = 0; reg < 4; ++reg){
        const int row = mt*16 + quad*4 + reg;
        Smf[row*260 + n] = acc[mt][j][reg] + bias;
      }
  }
  __syncthreads();
  {
    const int row_ = tid >> 3, seg = (tid & 7)*32;
    const int rowg = b*3136 + tile*32 + row_;
    float* dst = outp + (size_t)rowg*256 + seg;
    const float* srcl = &Smf[row_*260 + seg];
    #pragma unroll
    for (int i = 0; i < 8; ++i)
      *(float4*)(dst + i*4) = *(const float4*)(srcl + i*4);
  }
}

// ---------------------------------------------------------------------------
extern "C" void kernel_launch(void* const* d_in, const int* in_sizes, int n_in,
                              void* d_out, int out_size, void* d_ws, size_t ws_size,
                              hipStream_t stream)
{
  float* outp = (float*)d_out;
  const int FLAG_GRID = (out_size + 255)/256;

  if (n_in != 13) { flag_fill<<<FLAG_GRID,256,0,stream>>>(outp, out_size, 2000.f); return; }
  if (in_sizes[0] != 4*6*64*49*256) { flag_fill<<<FLAG_GRID,256,0,stream>>>(outp, out_size, 3000.f); return; }
  if (in_sizes[1] != 24) { flag_fill<<<FLAG_GRID,256,0,stream>>>(outp, out_size, 4000.f); return; }

  const size_t SZ_WFT  = (size_t)4*512*256*2;               //  1 MB (f16)
  const size_t SZ_BFF  = (size_t)4*512*sizeof(float);       //  8 KB
  const size_t SZ_WQF  = (size_t)2*256*256*2;               //  256 KB (f16)
  const size_t SZ_WAF  = (size_t)2*256*256*2;               //  256 KB (f16)
  const size_t SZ_Q    = (size_t)12544*256*2;               //  6.4 MB (f16)
  const size_t SZ_AOUT = (size_t)12544*256*2;               //  6.4 MB (f16)
  const size_t SZ_KW1  = (size_t)64*8*6*49*32*2;            //  9.63 MB / batch
  const size_t SZ_VM1  = SZ_KW1;                            //  unified layout
  const size_t FIXED   = SZ_WFT + SZ_BFF + SZ_WQF + SZ_WAF + SZ_Q + SZ_AOUT;
  if (ws_size < FIXED + SZ_KW1 + SZ_VM1) { flag_fill<<<FLAG_GRID,256,0,stream>>>(outp, out_size, 1000.f); return; }

  int nb = 1;
  if (ws_size >= FIXED + 4*(SZ_KW1 + SZ_VM1)) nb = 4;
  else if (ws_size >= FIXED + 2*(SZ_KW1 + SZ_VM1)) nb = 2;

  const float* x    = (const float*)d_in[0];
  const int*   mode = (const int*)d_in[1];
  const float* Wq   = (const float*)d_in[2];
  const float* bq   = (const float*)d_in[3];
  const float* Wk   = (const float*)d_in[4];
  const float* bk   = (const float*)d_in[5];
  const float* Wv   = (const float*)d_in[6];
  const float* bv   = (const float*)d_in[7];
  const float* Wa   = (const float*)d_in[8];
  const float* ba   = (const float*)d_in[9];
  const float* Ratt = (const float*)d_in[10];
  const float* Rmsg = (const float*)d_in[11];
  const float* post = (const float*)d_in[12];

  char* w = (char*)d_ws;
  u16* Wft   = (u16*)w;   w += SZ_WFT;
  float* bff = (float*)w; w += SZ_BFF;
  u16* Wqf   = (u16*)w;   w += SZ_WQF;
  u16* Waf   = (u16*)w;   w += SZ_WAF;
  u16* qbuf  = (u16*)w;   w += SZ_Q;
  u16* aout  = (u16*)w;   w += SZ_AOUT;
  u16* kwbuf = (u16*)w;   w += (size_t)nb*SZ_KW1;
  u16* vmbuf = (u16*)w;   w += (size_t)nb*SZ_VM1;

  fuse_all<<<1540, 512, 0, stream>>>(Wk, Wv, Ratt, Rmsg, Wq, Wa, bk, bv,
                                     Wft, bff, Wqf, Waf);
  gemm_qp<<<392, 256, 0, stream>>>(x, mode, Wqf, bq, qbuf);
  for (int b0 = 0; b0 < 4; b0 += nb) {
    gemm_kwv<<<nb*147, 512, 0, stream>>>(x, mode, Wft, bff, kwbuf, vmbuf, b0);
    attn_kernel<<<nb*512, 64, 0, stream>>>(qbuf, kwbuf, vmbuf, post, aout, b0);
  }
  gemm_op<<<392, 256, 0, stream>>>(aout, mode, Waf, ba, outp);
}

// Round 12
// 243.693 us; speedup vs baseline: 1.0737x; 1.0737x over previous
//
#include <hip/hip_runtime.h>

typedef unsigned short u16;
typedef unsigned int   u32;
typedef _Float16 f16;
typedef _Float16 h2  __attribute__((ext_vector_type(2)));
typedef _Float16 h8  __attribute__((ext_vector_type(8)));
typedef float    fx4 __attribute__((ext_vector_type(4)));

// ---- problem constants ----
// B=4 L=6 X=Y=8 -> 256 sites, W=49 window, D=256, h=8, dh=32
#define SCALE_Q 0.17677669529663687f

__device__ __forceinline__ u16 f2h_bits(float f){
  union{ f16 h; u16 u; } v; v.h = (f16)f; return v.u;
}
__device__ __forceinline__ u32 packh2(float a, float b){
  union{ h2 h; u32 u; } v; v.h = h2{(f16)a, (f16)b}; return v.u;
}
__device__ __forceinline__ h2 as_h2(u32 x){
  union{ u32 u; h2 h; } v; v.u = x; return v.h;
}
__device__ __forceinline__ h8 as_h8(uint4 u){
  union{ uint4 u; h8 h; } v; v.u = u; return v.h;
}

// diagnostic fill (fp32): encodes which runtime assumption failed
__global__ void flag_fill(float* out, int n, float v){
  int i = blockIdx.x*256 + threadIdx.x;
  if (i < n) out[i] = v;
}

// ---------------------------------------------------------------------------
// K0 (merged): fuse_w + fuse_b + fuse_qo in ONE launch. (unchanged)
// ---------------------------------------------------------------------------
__global__ __launch_bounds__(512) void fuse_all(
    const float* __restrict__ Wk, const float* __restrict__ Wv,
    const float* __restrict__ Ratt, const float* __restrict__ Rmsg,
    const float* __restrict__ Wq, const float* __restrict__ Wa,
    const float* __restrict__ bk, const float* __restrict__ bv,
    u16* __restrict__ Wft, float* __restrict__ bff,
    u16* __restrict__ Wqf, u16* __restrict__ Waf)
{
  const int blk = blockIdx.x;
  const int n = threadIdx.x;
  if (blk < 1024){
    const int rel = blk >> 8, d = blk & 255, ml = rel & 1;
    float acc = 0.f;
    if (n < 256) {
      const int h = n >> 5, p = n & 31;
      const float* wcol = Wk + (size_t)ml*65536 + (size_t)(h*32)*256 + d;
      const float* rrow = Ratt + ((size_t)(rel*8 + h)*32 + p)*32;
      #pragma unroll
      for (int q = 0; q < 32; ++q) acc += wcol[q*256] * rrow[q];
    } else {
      const int n2 = n - 256, h = n2 >> 5, qq = n2 & 31;
      const float* wcol = Wv + (size_t)ml*65536 + (size_t)(h*32)*256 + d;
      const float* rcol = Rmsg + ((size_t)(rel*8 + h)*32)*32 + qq;
      #pragma unroll
      for (int p2 = 0; p2 < 32; ++p2) acc += wcol[p2*256] * rcol[p2*32];
    }
    Wft[(size_t)rel*131072 + (size_t)(d >> 5)*16384 + (size_t)n*32 + (d & 31)] = f2h_bits(acc);
  } else if (blk < 1028){
    const int rel = blk - 1024, ml = rel & 1;
    float acc = 0.f;
    if (n < 256) {
      const int h = n >> 5, p = n & 31;
      const float* rrow = Ratt + ((size_t)(rel*8 + h)*32 + p)*32;
      #pragma unroll
      for (int q = 0; q < 32; ++q) acc += bk[ml*256 + h*32 + q] * rrow[q];
    } else {
      const int n2 = n - 256, h = n2 >> 5, qq = n2 & 31;
      const float* rcol = Rmsg + ((size_t)(rel*8 + h)*32)*32 + qq;
      #pragma unroll
      for (int p2 = 0; p2 < 32; ++p2) acc += bv[ml*256 + h*32 + p2] * rcol[p2*32];
    }
    bff[rel*512 + n] = acc;
  } else {
    const int bb = blk - 1028;
    const int t = bb >> 8, d = bb & 255;
    if (n < 256){
      float v = Wq[(size_t)t*65536 + (size_t)n*256 + d] * SCALE_Q;
      Wqf[(size_t)t*65536 + (size_t)(d >> 5)*8192 + (size_t)n*32 + (d & 31)] = f2h_bits(v);
    } else {
      const int e = n - 256;
      float v = Wa[(size_t)t*65536 + (size_t)e*256 + d];
      Waf[(size_t)t*65536 + (size_t)(d >> 5)*8192 + (size_t)e*32 + (d & 31)] = f2h_bits(v);
    }
  }
}

// ---------------------------------------------------------------------------
// K1 v9: fused kw / v_msg projection GEMM — MFMA (16x16x32 f16).
// BM=64, BN=512, 512 threads (8 waves), grid = nb*294 (v7b structure;
// the r11 two-tile variant REGRESSED 70->75 and is reverted).
// KEY CHANGE: register budget 132 -> 116 so TWO blocks co-reside per CU.
// v7b at 68 VGPR + 64 AGPR = 132 > 128 allowed only 3 waves/SIMD (1.5
// blocks) -> zero cross-block overlap, every phase serial (occupancy 19%).
// v9: B pipeline 3 slots -> 2 slots (-16 VGPR) + __launch_bounds__(512,4)
// pins 4 waves/SIMD = 2 blocks/CU; block B's compute hides block A's
// A-stage HBM latency and epilogue stores.
// 2-slot counted vmcnt: prologue slots 0,1 drained by A-stage barrier;
// refills issued at steps 0..5; steps 2-6 wait vmcnt(4), step 7 vmcnt(0).
// Outputs kw/vm[bloc][xy][h][l][ef][p] (f16) — unchanged.
// ---------------------------------------------------------------------------
#define ASTRIDE 264   // u16 elements per LDS row (16B-aligned, conflict-light)

__global__ __launch_bounds__(512, 4) void gemm_kwv(
    const float* __restrict__ x, const int* __restrict__ mode,
    const u16* __restrict__ Wft, const float* __restrict__ bff,
    u16* __restrict__ kw, u16* __restrict__ vm, int b0)
{
  __shared__ u16 Smem[64*ASTRIDE];   // 33.8 KB: A-tile, then epilogue buffer
  const int rowT  = blockIdx.x;              // bloc*294 + l*49 + tile
  const int bloc = rowT / 294;
  const int rem  = rowT % 294;
  const int l = rem / 49, tile = rem % 49;
  const int b = b0 + bloc;
  const int rel = mode[b*6]*2 + mode[b*6 + l];
  const float* Abase = x + ((size_t)(b*6 + l)*3136 + (size_t)tile*64)*256;
  const int tid  = threadIdx.x;
  const int wave = tid >> 6, lane = tid & 63;
  const int quad = lane >> 4, l15 = lane & 15;

  // per-lane B base in k-step-major layout [rel][s][n][32]; wave owns 64 cols
  const u16* Bp = Wft + (size_t)rel*131072 + (size_t)((wave << 6) + l15)*32 + (quad << 3);

  // ---- prologue: pin k-steps 0..1 into 2 rotating slots (8 loads) ----
  uint4 breg[2][4];
  #pragma unroll
  for (int s = 0; s < 2; ++s)
    #pragma unroll
    for (int j = 0; j < 4; ++j){
      const u16* ap = Bp + (size_t)s*16384 + j*512;
      asm volatile("global_load_dwordx4 %0, %1, off" : "=v"(breg[s][j]) : "v"(ap));
    }

  // ---- stage A (64x256 fp32 -> f16 LDS), wave-linear coalesced ----
  #pragma unroll
  for (int i = 0; i < 8; ++i){
    float4 f = *(const float4*)(Abase + (size_t)i*2048 + tid*4);
    const int row = i*8 + (tid >> 6), col = (tid & 63)*4;
    uint2 pk; pk.x = packh2(f.x, f.y); pk.y = packh2(f.z, f.w);
    *(uint2*)&Smem[row*ASTRIDE + col] = pk;
  }
  __syncthreads();   // compiler drains vmcnt before s_barrier: slots 0,1 ready

  fx4 acc[4][4];
  #pragma unroll
  for (int mt = 0; mt < 4; ++mt)
    #pragma unroll
    for (int j = 0; j < 4; ++j) acc[mt][j] = fx4{0,0,0,0};

  const u16* As = &Smem[l15*ASTRIDE + (quad << 3)];

  // ---- k-loop: 8 steps, 2-slot rotation, counted vmcnt ----
  // at top of step s>=2: refills from steps s-2 (consumed slot, wait) and
  // s-1 (other slot, 4 newer loads in flight) -> vmcnt(4).
  #pragma unroll
  for (int s = 0; s < 8; ++s){
    if (s >= 2 && s <= 6)      { asm volatile("s_waitcnt vmcnt(4)" ::: "memory"); }
    else if (s == 7)           { asm volatile("s_waitcnt vmcnt(0)" ::: "memory"); }
    __builtin_amdgcn_sched_barrier(0);
    h8 af[4];
    #pragma unroll
    for (int mt = 0; mt < 4; ++mt)
      af[mt] = *(const h8*)(As + (mt*16)*ASTRIDE + s*32);
    const int slot = s & 1;
    #pragma unroll
    for (int j = 0; j < 4; ++j){
      h8 bf = as_h8(breg[slot][j]);
      #pragma unroll
      for (int mt = 0; mt < 4; ++mt)
        acc[mt][j] = __builtin_amdgcn_mfma_f32_16x16x32_f16(af[mt], bf, acc[mt][j], 0, 0, 0);
    }
    if (s < 6){
      #pragma unroll
      for (int j = 0; j < 4; ++j){
        const u16* ap = Bp + (size_t)(s + 2)*16384 + j*512;
        asm volatile("global_load_dwordx4 %0, %1, off" : "=v"(breg[slot][j]) : "v"(ap));
      }
    }
  }

  // ---- epilogue: LDS transpose, two halves (kw = waves 0-3 / vm = 4-7) ----
  const int row_ = tid >> 3;        // 0..63
  const int hsel = tid & 7;         // 0..7
  const int r_g  = tile*64 + row_;  // 0..3135
  const int xy   = r_g / 49, ef = r_g - xy*49;

  #pragma unroll
  for (int half = 0; half < 2; ++half){
    __syncthreads();   // protect Smem (A-tile reads / previous half's reads)
    if ((wave >> 2) == half){
      #pragma unroll
      for (int j = 0; j < 4; ++j){
        const int n   = wave*64 + j*16 + l15;   // 0..511
        const int col = n & 255;
        const float bias = bff[rel*512 + n];
        #pragma unroll
        for (int mt = 0; mt < 4; ++mt){
          #pragma unroll
          for (int reg = 0; reg < 4; ++reg){
            const int row = mt*16 + quad*4 + reg;
            Smem[row*ASTRIDE + col] = f2h_bits(acc[mt][j][reg] + bias);
          }
        }
      }
    }
    __syncthreads();
    u16* dbuf = half ? vm : kw;
    u16* dst  = dbuf + ((((size_t)(bloc*64 + xy)*8 + hsel)*6 + l)*49 + ef)*32;
    const u16* srcl = &Smem[row_*ASTRIDE + hsel*32];
    *(uint4*)(dst)      = *(const uint4*)(srcl);
    *(uint4*)(dst + 8)  = *(const uint4*)(srcl + 8);
    *(uint4*)(dst + 16) = *(const uint4*)(srcl + 16);
    *(uint4*)(dst + 24) = *(const uint4*)(srcl + 24);
  }
}

// ---------------------------------------------------------------------------
// K2 v2: q projection (l=0 only) — MFMA. BM=32, BN=256, grid = 4*98. (unchanged)
// ---------------------------------------------------------------------------
__global__ __launch_bounds__(256, 2) void gemm_qp(
    const float* __restrict__ x, const int* __restrict__ mode,
    const u16* __restrict__ Wqf, const float* __restrict__ bq,
    u16* __restrict__ qbuf)
{
  __shared__ u16 Smem[32*ASTRIDE];
  const int rowT = blockIdx.x;       // b*98 + tile
  const int b = rowT / 98, tile = rowT % 98;
  const int m0 = mode[b*6];
  const float* Abase = x + ((size_t)(b*6)*3136 + (size_t)tile*32)*256;
  const int tid = threadIdx.x;
  const int wave = tid >> 6, lane = tid & 63;
  const int quad = lane >> 4, l15 = lane & 15;

  const u16* Bp = Wqf + (size_t)m0*65536 + (size_t)((wave << 6) + l15)*32 + (quad << 3);
  uint4 breg[32];
  #pragma unroll
  for (int s = 0; s < 8; ++s)
    #pragma unroll
    for (int j = 0; j < 4; ++j){
      const u16* ap = Bp + (size_t)s*8192 + j*512;
      asm volatile("global_load_dwordx4 %0, %1, off" : "=v"(breg[s*4+j]) : "v"(ap));
    }

  {
    const int r = tid >> 3, cseg = (tid & 7)*32;
    const float* src = Abase + (size_t)r*256 + cseg;
    u16* dst = &Smem[r*ASTRIDE + cseg];
    #pragma unroll
    for (int i = 0; i < 4; ++i){
      float4 f0 = *(const float4*)(src + i*8);
      float4 f1 = *(const float4*)(src + i*8 + 4);
      uint4 pk;
      pk.x = packh2(f0.x, f0.y); pk.y = packh2(f0.z, f0.w);
      pk.z = packh2(f1.x, f1.y); pk.w = packh2(f1.z, f1.w);
      *(uint4*)(dst + i*8) = pk;
    }
  }
  __syncthreads();

  fx4 acc[2][4];
  #pragma unroll
  for (int mt = 0; mt < 2; ++mt)
    #pragma unroll
    for (int j = 0; j < 4; ++j) acc[mt][j] = fx4{0,0,0,0};

  const u16* As0 = &Smem[l15*ASTRIDE + (quad << 3)];
  const u16* As1 = As0 + 16*ASTRIDE;
  asm volatile("s_waitcnt vmcnt(0)" ::: "memory");
  __builtin_amdgcn_sched_barrier(0);
  #pragma unroll
  for (int s = 0; s < 8; ++s){
    h8 af0 = *(const h8*)(As0 + s*32);
    h8 af1 = *(const h8*)(As1 + s*32);
    #pragma unroll
    for (int j = 0; j < 4; ++j){
      h8 bf = as_h8(breg[s*4+j]);
      acc[0][j] = __builtin_amdgcn_mfma_f32_16x16x32_f16(af0, bf, acc[0][j], 0, 0, 0);
      acc[1][j] = __builtin_amdgcn_mfma_f32_16x16x32_f16(af1, bf, acc[1][j], 0, 0, 0);
    }
  }

  __syncthreads();
  #pragma unroll
  for (int j = 0; j < 4; ++j){
    const int n = wave*64 + j*16 + l15;
    const float bias = bq[m0*256 + n] * SCALE_Q;
    #pragma unroll
    for (int mt = 0; mt < 2; ++mt)
      #pragma unroll
      for (int reg = 0; reg < 4; ++reg){
        const int row = mt*16 + quad*4 + reg;
        Smem[row*ASTRIDE + n] = f2h_bits(acc[mt][j][reg] + bias);
      }
  }
  __syncthreads();
  {
    const int row_ = tid >> 3, hsel = tid & 7;
    const int r_g = tile*32 + row_;
    const int xy = r_g / 49, ef = r_g - xy*49;
    u16* dst = qbuf + (((size_t)(b*64 + xy)*8 + hsel)*49 + ef)*32;
    const u16* srcl = &Smem[row_*ASTRIDE + hsel*32];
    *(uint4*)(dst)      = *(const uint4*)(srcl);
    *(uint4*)(dst + 8)  = *(const uint4*)(srcl + 8);
    *(uint4*)(dst + 16) = *(const uint4*)(srcl + 16);
    *(uint4*)(dst + 24) = *(const uint4*)(srcl + 24);
  }
}

// ---------------------------------------------------------------------------
// K3 v8: attention — ONE WAVE per (bloc,xy,h), MFMA, LDS double-buffer,
// all-C++ staging. (unchanged from r9 — passed)
// ---------------------------------------------------------------------------
#define LGKM0  do{ asm volatile("s_waitcnt lgkmcnt(0)" ::: "memory"); \
                   __builtin_amdgcn_sched_barrier(0); }while(0)

__device__ __forceinline__ void scatter_v(u16* VTb, int i4, uint4 vv){
  const int ef = i4 >> 2, pb = (i4 & 3)*8, c0 = ef >> 3;
  u16* vt = VTb + (ef & 7);
  vt[(pb+0)*64 + ((c0 ^ 0) << 3)] = (u16)(vv.x & 0xFFFFu);
  vt[(pb+1)*64 + ((c0 ^ 1) << 3)] = (u16)(vv.x >> 16);
  vt[(pb+2)*64 + ((c0 ^ 2) << 3)] = (u16)(vv.y & 0xFFFFu);
  vt[(pb+3)*64 + ((c0 ^ 3) << 3)] = (u16)(vv.y >> 16);
  vt[(pb+4)*64 + ((c0 ^ 4) << 3)] = (u16)(vv.z & 0xFFFFu);
  vt[(pb+5)*64 + ((c0 ^ 5) << 3)] = (u16)(vv.z >> 16);
  vt[(pb+6)*64 + ((c0 ^ 6) << 3)] = (u16)(vv.w & 0xFFFFu);
  vt[(pb+7)*64 + ((c0 ^ 7) << 3)] = (u16)(vv.w >> 16);
}

__global__ __launch_bounds__(64) void attn_kernel(
    const u16* __restrict__ qbuf, const u16* __restrict__ kw,
    const u16* __restrict__ vm,   const float* __restrict__ post,
    u16* __restrict__ aout, int b0)
{
  __shared__ u32 Ks[2*64*16];   // 2 buffers: K rows [ke][p], pad rows zero  8KB
  __shared__ u16 VT[2*32*64];   // 2 buffers: V^T [p][ke] chunk-XOR-swizzled 8KB
  __shared__ u16 PQ[64*64];     // Q staging [qi][32] -> P^T [qi][ke] swz    8KB
  __shared__ float poss[169];

  const int bloc  = blockIdx.x >> 9;
  const int local = blockIdx.x & 511;      // xy*8+h
  const int h = local & 7, xy = local >> 3;
  const int bxy = (b0 + bloc)*64 + xy;
  const int lane = threadIdx.x;            // 0..63
  const int quad = lane >> 4, l15 = lane & 15;

  const size_t kvbase = ((size_t)(bloc*64 + xy)*8 + h)*6;

  for (int i = lane; i < 169; i += 64) poss[i] = post[i*8 + h];
  for (int i = lane; i < 480; i += 64){                     // K pad rows, both bufs
    const int bb = i / 240, o = i - bb*240;
    Ks[bb*1024 + 784 + o] = 0;
  }
  for (int i = lane; i < 1024; i += 64){                    // VT pad ke 48..63, both bufs
    const int bb = i >> 9, r = i & 511;
    const int p = r >> 4, ke = 48 + (r & 15);
    VT[bb*2048 + p*64 + ((((ke >> 3) ^ (p & 7)) & 7) << 3) + (ke & 7)] = 0;
  }
  { const u16* qsrc = qbuf + (size_t)(bxy*8 + h)*1568;      // Q rows -> PQ[qi][32]
    for (int i = lane; i < 196; i += 64)
      *(uint4*)&PQ[(i >> 2)*32 + (i & 3)*8] = *(const uint4*)(qsrc + (size_t)i*8);
    const uint4 z4 = make_uint4(0,0,0,0);
    for (int i = lane; i < 60; i += 64)                     // rows 49..63 zero
      *(uint4*)&PQ[1568 + i*8] = z4;
  }
  // ---- stage z=0 into buffer 0 ----
  { const uint4* ksrc = (const uint4*)((const u32*)kw + kvbase*784);
    for (int i = lane; i < 196; i += 64) ((uint4*)Ks)[i] = ksrc[i];
    const uint4* vsrc = (const uint4*)((const u32*)vm + kvbase*784);
    for (int i = lane; i < 196; i += 64) scatter_v(VT, i, vsrc[i]);
  }
  LGKM0;   // single-wave block: lgkmcnt(0) replaces __syncthreads

  // Q B-frags (persist across all z)
  h8 qf[4];
  #pragma unroll
  for (int nt = 0; nt < 4; ++nt)
    qf[nt] = *(const h8*)&PQ[(nt*16 + l15)*32 + quad*8];

  // bias C-in frags (persist): element (ke = mt*16+quad*4+reg, qi = nt*16+l15)
  fx4 bias[4][4];
  { int qa[4], qb[4];
    #pragma unroll
    for (int nt = 0; nt < 4; ++nt){
      const int qi = nt*16 + l15; qa[nt] = qi/7; qb[nt] = qi - qa[nt]*7;
    }
    #pragma unroll
    for (int mt = 0; mt < 4; ++mt)
      #pragma unroll
      for (int reg = 0; reg < 4; ++reg){
        const int ke = mt*16 + quad*4 + reg;
        const int ka = ke/7, kb = ke - ka*7;
        #pragma unroll
        for (int nt = 0; nt < 4; ++nt){
          const int qi = nt*16 + l15;
          float bv;
          if (ke > 48)      bv = -1e30f;
          else if (qi > 48) bv = 0.f;
          else              bv = poss[(qa[nt] - ka + 6)*13 + (qb[nt] - kb + 6)];
          bias[mt][nt][reg] = bv;
        }
      }
  }

  float mprev[4], lsum[4];
  fx4 Oacc[2][4];
  #pragma unroll
  for (int nt = 0; nt < 4; ++nt){
    mprev[nt] = -1e30f; lsum[nt] = 0.f;
    Oacc[0][nt] = fx4{0,0,0,0}; Oacc[1][nt] = fx4{0,0,0,0};
  }

  int cur = 0;
  for (int z = 0; z < 6; ++z){
    // ---- prefetch z+1 into C++ locals ----
    uint4 kn0, kn1, kn2, kn3, vn0, vn1, vn2, vn3;
    if (z < 5){
      const uint4* ksrc = (const uint4*)((const u32*)kw + (kvbase + z + 1)*784);
      const uint4* vsrc = (const uint4*)((const u32*)vm + (kvbase + z + 1)*784);
      kn0 = ksrc[lane]; kn1 = ksrc[64 + lane]; kn2 = ksrc[128 + lane];
      vn0 = vsrc[lane]; vn1 = vsrc[64 + lane]; vn2 = vsrc[128 + lane];
      if (lane < 4){ kn3 = ksrc[192 + lane]; vn3 = vsrc[192 + lane]; }
    }

    const u32* KsC = Ks + cur*1024;
    const u16* VTC = VT + cur*2048;

    // ---- S^T = K·Q^T + bias (16 MFMA) ----
    h8 kf[4];
    #pragma unroll
    for (int mt = 0; mt < 4; ++mt)
      kf[mt] = *(const h8*)((const u16*)KsC + (mt*16 + l15)*32 + quad*8);
    fx4 S[4][4];
    #pragma unroll
    for (int mt = 0; mt < 4; ++mt)
      #pragma unroll
      for (int nt = 0; nt < 4; ++nt)
        S[mt][nt] = __builtin_amdgcn_mfma_f32_16x16x32_f16(kf[mt], qf[nt], bias[mt][nt], 0, 0, 0);

    // ---- online softmax per qi-column group nt ----
    #pragma unroll
    for (int nt = 0; nt < 4; ++nt){
      float cm = S[0][nt][0];
      #pragma unroll
      for (int mt = 0; mt < 4; ++mt)
        #pragma unroll
        for (int r = 0; r < 4; ++r) cm = fmaxf(cm, S[mt][nt][r]);
      cm = fmaxf(cm, __shfl_xor(cm, 16));
      cm = fmaxf(cm, __shfl_xor(cm, 32));
      const float mnew = fmaxf(mprev[nt], cm);
      const float alpha = __expf(mprev[nt] - mnew);
      mprev[nt] = mnew;
      float sum = 0.f;
      #pragma unroll
      for (int mt = 0; mt < 4; ++mt)
        #pragma unroll
        for (int r = 0; r < 4; ++r){
          float e = __expf(S[mt][nt][r] - mnew); S[mt][nt][r] = e; sum += e;
        }
      sum += __shfl_xor(sum, 16);
      sum += __shfl_xor(sum, 32);
      lsum[nt] = lsum[nt]*alpha + sum;
      #pragma unroll
      for (int r = 0; r < 4; ++r){ Oacc[0][nt][r] *= alpha; Oacc[1][nt][r] *= alpha; }
    }

    // ---- pack P^T into PQ (swizzled): ke chunk = mt*2 + (quad>>1) ----
    #pragma unroll
    for (int nt = 0; nt < 4; ++nt){
      const int qi = nt*16 + l15;
      u16* prow = &PQ[qi*64 + ((quad & 1) << 2)];
      #pragma unroll
      for (int mt = 0; mt < 4; ++mt){
        const int chk = (mt*2 + (quad >> 1)) ^ (l15 & 7);
        uint2 w;
        w.x = packh2(S[mt][nt][0], S[mt][nt][1]);
        w.y = packh2(S[mt][nt][2], S[mt][nt][3]);
        *(uint2*)(prow + (chk << 3)) = w;
      }
    }
    LGKM0;   // P^T visible

    // ---- O^T += V^T · P^T (16 MFMA over 2 k-steps) ----
    #pragma unroll
    for (int ks = 0; ks < 2; ++ks){
      h8 vf[2];
      #pragma unroll
      for (int m2 = 0; m2 < 2; ++m2)
        vf[m2] = *(const h8*)&VTC[(m2*16 + l15)*64 + (((ks*4 + quad) ^ (l15 & 7)) << 3)];
      #pragma unroll
      for (int nt = 0; nt < 4; ++nt){
        h8 pf = *(const h8*)&PQ[(nt*16 + l15)*64 + (((ks*4 + quad) ^ (l15 & 7)) << 3)];
        Oacc[0][nt] = __builtin_amdgcn_mfma_f32_16x16x32_f16(vf[0], pf, Oacc[0][nt], 0, 0, 0);
        Oacc[1][nt] = __builtin_amdgcn_mfma_f32_16x16x32_f16(vf[1], pf, Oacc[1][nt], 0, 0, 0);
      }
    }

    // ---- stage z+1 into the OTHER buffer (WAR-free by construction) ----
    if (z < 5){
      u32* KsN = Ks + (cur ^ 1)*1024;
      u16* VTN = VT + (cur ^ 1)*2048;
      ((uint4*)KsN)[lane]       = kn0;
      ((uint4*)KsN)[64 + lane]  = kn1;
      ((uint4*)KsN)[128 + lane] = kn2;
      scatter_v(VTN, lane,       vn0);
      scatter_v(VTN, 64 + lane,  vn1);
      scatter_v(VTN, 128 + lane, vn2);
      if (lane < 4){
        ((uint4*)KsN)[192 + lane] = kn3;
        scatter_v(VTN, 192 + lane, vn3);
      }
    }
    LGKM0;   // staging visible before next iteration reads it
    cur ^= 1;
  }

  // ---- normalize + store via LDS roundtrip ----
  #pragma unroll
  for (int nt = 0; nt < 4; ++nt){
    const int qi = nt*16 + l15;
    if (qi < 49){
      const float inv = 1.f / lsum[nt];
      #pragma unroll
      for (int m2 = 0; m2 < 2; ++m2){
        uint2 w;
        w.x = packh2(Oacc[m2][nt][0]*inv, Oacc[m2][nt][1]*inv);
        w.y = packh2(Oacc[m2][nt][2]*inv, Oacc[m2][nt][3]*inv);
        *(uint2*)&PQ[qi*32 + m2*16 + quad*4] = w;
      }
    }
  }
  LGKM0;
  { u16* obase = aout + (size_t)bxy*12544 + h*32;
    for (int i = lane; i < 196; i += 64){
      const int r = i >> 2, c = (i & 3)*8;
      *(uint4*)(obase + (size_t)r*256 + c) = *(const uint4*)&PQ[r*32 + c];
    }
  }
}

// ---------------------------------------------------------------------------
// K4 v2: final projection — MFMA. A = aout f16, B = Waf[m0] k-step-major,
// bias ba, fp32 out via LDS float transpose. BM=32, BN=256, grid = 4*98.
// ---------------------------------------------------------------------------
__global__ __launch_bounds__(256, 2) void gemm_op(
    const u16* __restrict__ aout, const int* __restrict__ mode,
    const u16* __restrict__ Waf, const float* __restrict__ ba,
    float* __restrict__ outp)
{
  __shared__ float Smf[32*260];          // 33.3 KB; low half doubles as u16 A-tile
  u16* Smem = (u16*)Smf;
  const int rowT = blockIdx.x;       // b*98 + tile
  const int b = rowT / 98, tile = rowT % 98;
  const int m0 = mode[b*6];
  const u16* Abase = aout + ((size_t)b*3136 + (size_t)tile*32)*256;
  const int tid = threadIdx.x;
  const int wave = tid >> 6, lane = tid & 63;
  const int quad = lane >> 4, l15 = lane & 15;

  const u16* Bp = Waf + (size_t)m0*65536 + (size_t)((wave << 6) + l15)*32 + (quad << 3);
  uint4 breg[32];
  #pragma unroll
  for (int s = 0; s < 8; ++s)
    #pragma unroll
    for (int j = 0; j < 4; ++j){
      const u16* ap = Bp + (size_t)s*8192 + j*512;
      asm volatile("global_load_dwordx4 %0, %1, off" : "=v"(breg[s*4+j]) : "v"(ap));
    }

  {
    const int r = tid >> 3, cseg = (tid & 7)*32;
    const u16* src = Abase + (size_t)r*256 + cseg;
    u16* dst = &Smem[r*ASTRIDE + cseg];
    #pragma unroll
    for (int i = 0; i < 4; ++i)
      *(uint4*)(dst + i*8) = *(const uint4*)(src + i*8);
  }
  __syncthreads();

  fx4 acc[2][4];
  #pragma unroll
  for (int mt = 0; mt < 2; ++mt)
    #pragma unroll
    for (int j = 0; j < 4; ++j) acc[mt][j] = fx4{0,0,0,0};

  const u16* As0 = &Smem[l15*ASTRIDE + (quad << 3)];
  const u16* As1 = As0 + 16*ASTRIDE;
  asm volatile("s_waitcnt vmcnt(0)" ::: "memory");
  __builtin_amdgcn_sched_barrier(0);
  #pragma unroll
  for (int s = 0; s < 8; ++s){
    h8 af0 = *(const h8*)(As0 + s*32);
    h8 af1 = *(const h8*)(As1 + s*32);
    #pragma unroll
    for (int j = 0; j < 4; ++j){
      h8 bf = as_h8(breg[s*4+j]);
      acc[0][j] = __builtin_amdgcn_mfma_f32_16x16x32_f16(af0, bf, acc[0][j], 0, 0, 0);
      acc[1][j] = __builtin_amdgcn_mfma_f32_16x16x32_f16(af1, bf, acc[1][j], 0, 0, 0);
    }
  }

  __syncthreads();
  #pragma unroll
  for (int j = 0; j < 4; ++j){
    const int n = wave*64 + j*16 + l15;
    const float bias = ba[m0*256 + n];
    #pragma unroll
    for (int mt = 0; mt < 2; ++mt)
      #pragma unroll
      for (int reg = 0; reg < 4; ++reg){
        const int row = mt*16 + quad*4 + reg;
        Smf[row*260 + n] = acc[mt][j][reg] + bias;
      }
  }
  __syncthreads();
  {
    const int row_ = tid >> 3, seg = (tid & 7)*32;
    const int rowg = b*3136 + tile*32 + row_;
    float* dst = outp + (size_t)rowg*256 + seg;
    const float* srcl = &Smf[row_*260 + seg];
    #pragma unroll
    for (int i = 0; i < 8; ++i)
      *(float4*)(dst + i*4) = *(const float4*)(srcl + i*4);
  }
}

// ---------------------------------------------------------------------------
extern "C" void kernel_launch(void* const* d_in, const int* in_sizes, int n_in,
                              void* d_out, int out_size, void* d_ws, size_t ws_size,
                              hipStream_t stream)
{
  float* outp = (float*)d_out;
  const int FLAG_GRID = (out_size + 255)/256;

  if (n_in != 13) { flag_fill<<<FLAG_GRID,256,0,stream>>>(outp, out_size, 2000.f); return; }
  if (in_sizes[0] != 4*6*64*49*256) { flag_fill<<<FLAG_GRID,256,0,stream>>>(outp, out_size, 3000.f); return; }
  if (in_sizes[1] != 24) { flag_fill<<<FLAG_GRID,256,0,stream>>>(outp, out_size, 4000.f); return; }

  const size_t SZ_WFT  = (size_t)4*512*256*2;               //  1 MB (f16)
  const size_t SZ_BFF  = (size_t)4*512*sizeof(float);       //  8 KB
  const size_t SZ_WQF  = (size_t)2*256*256*2;               //  256 KB (f16)
  const size_t SZ_WAF  = (size_t)2*256*256*2;               //  256 KB (f16)
  const size_t SZ_Q    = (size_t)12544*256*2;               //  6.4 MB (f16)
  const size_t SZ_AOUT = (size_t)12544*256*2;               //  6.4 MB (f16)
  const size_t SZ_KW1  = (size_t)64*8*6*49*32*2;            //  9.63 MB / batch
  const size_t SZ_VM1  = SZ_KW1;                            //  unified layout
  const size_t FIXED   = SZ_WFT + SZ_BFF + SZ_WQF + SZ_WAF + SZ_Q + SZ_AOUT;
  if (ws_size < FIXED + SZ_KW1 + SZ_VM1) { flag_fill<<<FLAG_GRID,256,0,stream>>>(outp, out_size, 1000.f); return; }

  int nb = 1;
  if (ws_size >= FIXED + 4*(SZ_KW1 + SZ_VM1)) nb = 4;
  else if (ws_size >= FIXED + 2*(SZ_KW1 + SZ_VM1)) nb = 2;

  const float* x    = (const float*)d_in[0];
  const int*   mode = (const int*)d_in[1];
  const float* Wq   = (const float*)d_in[2];
  const float* bq   = (const float*)d_in[3];
  const float* Wk   = (const float*)d_in[4];
  const float* bk   = (const float*)d_in[5];
  const float* Wv   = (const float*)d_in[6];
  const float* bv   = (const float*)d_in[7];
  const float* Wa   = (const float*)d_in[8];
  const float* ba   = (const float*)d_in[9];
  const float* Ratt = (const float*)d_in[10];
  const float* Rmsg = (const float*)d_in[11];
  const float* post = (const float*)d_in[12];

  char* w = (char*)d_ws;
  u16* Wft   = (u16*)w;   w += SZ_WFT;
  float* bff = (float*)w; w += SZ_BFF;
  u16* Wqf   = (u16*)w;   w += SZ_WQF;
  u16* Waf   = (u16*)w;   w += SZ_WAF;
  u16* qbuf  = (u16*)w;   w += SZ_Q;
  u16* aout  = (u16*)w;   w += SZ_AOUT;
  u16* kwbuf = (u16*)w;   w += (size_t)nb*SZ_KW1;
  u16* vmbuf = (u16*)w;   w += (size_t)nb*SZ_VM1;

  fuse_all<<<1540, 512, 0, stream>>>(Wk, Wv, Ratt, Rmsg, Wq, Wa, bk, bv,
                                     Wft, bff, Wqf, Waf);
  gemm_qp<<<392, 256, 0, stream>>>(x, mode, Wqf, bq, qbuf);
  for (int b0 = 0; b0 < 4; b0 += nb) {
    gemm_kwv<<<nb*294, 512, 0, stream>>>(x, mode, Wft, bff, kwbuf, vmbuf, b0);
    attn_kernel<<<nb*512, 64, 0, stream>>>(qbuf, kwbuf, vmbuf, post, aout, b0);
  }
  gemm_op<<<392, 256, 0, stream>>>(aout, mode, Waf, ba, outp);
}